// Round 1
// baseline (518.073 us; speedup 1.0000x reference)
//
#include <hip/hip_runtime.h>

// out[a,bc,d,g] = (1/3) * sum_{e,f} T1[a,bc,d,e,f] * T2[bc,e,f,g]
// A=4, BC=786432; T1 slab 27 f32, T2 slab 27 f32, out slab 9 f32.
// Memory-bound: ~538 MB total traffic -> ~85us floor at 6.3 TB/s.
//
// v2: stage via __builtin_amdgcn_global_load_lds (16B/lane) instead of
// global->VGPR->LDS round trip. LDS layout is linear per segment, which is
// exactly the wave-uniform-base + lane*16 pattern the DMA path requires.

#define A_        4
#define BC_       786432
#define TILE_     64          // bc slabs per block
#define NTHREADS  256         // 4 a * 64 bc_local

#define SEG_BYTES    6912     // TILE_*27*4 bytes per staged segment
#define CHUNK_BYTES  1024     // 64 lanes * 16 B
#define FULL_CHUNKS  6        // 6 KiB of each segment in full wave-chunks
#define TAIL_LANES   48       // 768 B tail = 48 lanes * 16 B
#define NCHUNK       35       // 5 segments * 7 chunks

#define T1_A_BYTES     84934656u   // BC_*27*4 (a-stride of T1, bytes)
#define OUT_A_STRIDE4  1769472     // BC_*9/4  (a-stride of Out, float4)
#define OUT_TILE4      144         // TILE_*9/4 per a-region

__device__ __forceinline__ void load_lds16(const void* g, void* l) {
    __builtin_amdgcn_global_load_lds(
        (const __attribute__((address_space(1))) void*)g,
        (__attribute__((address_space(3))) void*)l,
        16, 0, 0);
}

__global__ __launch_bounds__(NTHREADS, 4)
void prod_einsum_kernel(const float* __restrict__ T1,
                        const float* __restrict__ T2,
                        float* __restrict__ Out) {
    // smem: [0, 6912) floats = 4 T1 segments; [6912, 8640) = T2 segment.
    // After compute, front of smem is reused as output staging (2304 floats).
    __shared__ float smem[8640];
    float4* smem4 = (float4*)smem;
    float4* Outv  = (float4*)Out;

    const int tid  = threadIdx.x;
    const int lane = tid & 63;
    const int wave = tid >> 6;
    const int blk  = blockIdx.x;

    // ---- Stage 5 segments (4x T1-a, 1x T2) via async global->LDS ----
    {
        const char* t1b  = (const char*)T1 + (size_t)blk * SEG_BYTES;
        const char* t2b  = (const char*)T2 + (size_t)blk * SEG_BYTES;
        char*       lds0 = (char*)smem;
        for (int c = wave; c < NCHUNK; c += 4) {
            const int s = c / 7;              // segment 0..4
            const int k = c - s * 7;          // chunk within segment 0..6
            const char* gseg = (s < 4) ? (t1b + (size_t)s * T1_A_BYTES) : t2b;
            const char* gsrc = gseg + k * CHUNK_BYTES + lane * 16;
            char*       ldst = lds0 + s * SEG_BYTES + k * CHUNK_BYTES;
            if (k < FULL_CHUNKS) {
                load_lds16(gsrc, ldst);           // full 1 KiB chunk
            } else if (lane < TAIL_LANES) {
                load_lds16(gsrc, ldst);           // 768 B tail
            }
        }
    }
    __syncthreads();   // compiler emits s_waitcnt vmcnt(0) before s_barrier

    // ---- Compute: thread = (a, bc_local) ----
    const int a = tid >> 6;
    const int l = tid & 63;
    const float* t1 = smem + (a * TILE_ + l) * 27;
    const float* t2 = smem + 6912 + l * 27;

    float r1[27], r2[27];
    #pragma unroll
    for (int i = 0; i < 27; ++i) r1[i] = t1[i];
    #pragma unroll
    for (int i = 0; i < 27; ++i) r2[i] = t2[i];

    float acc[9];
    #pragma unroll
    for (int d = 0; d < 3; ++d) {
        #pragma unroll
        for (int g = 0; g < 3; ++g) {
            float s = 0.0f;
            #pragma unroll
            for (int e = 0; e < 3; ++e) {
                #pragma unroll
                for (int f = 0; f < 3; ++f) {
                    s += r1[d * 9 + e * 3 + f] * r2[e * 9 + f * 3 + g];
                }
            }
            acc[d * 3 + g] = s * (1.0f / 3.0f);
        }
    }

    __syncthreads();  // all LDS reads done; safe to overwrite front of smem

    // ---- Stage output: (a, l, 9) packed = 2304 floats ----
    #pragma unroll
    for (int i = 0; i < 9; ++i) {
        smem[(a * TILE_ + l) * 9 + i] = acc[i];
    }
    __syncthreads();

    // ---- Coalesced write: 4 regions of 144 float4, flattened to 576 ----
    for (int j = tid; j < 4 * OUT_TILE4; j += NTHREADS) {
        int a2 = j / OUT_TILE4;
        int r  = j - a2 * OUT_TILE4;
        Outv[a2 * OUT_A_STRIDE4 + blk * OUT_TILE4 + r] = smem4[j];
    }
}

extern "C" void kernel_launch(void* const* d_in, const int* in_sizes, int n_in,
                              void* d_out, int out_size, void* d_ws, size_t ws_size,
                              hipStream_t stream) {
    const float* T1 = (const float*)d_in[0];
    const float* T2 = (const float*)d_in[1];
    float* Out = (float*)d_out;
    prod_einsum_kernel<<<BC_ / TILE_, NTHREADS, 0, stream>>>(T1, T2, Out);
}